// Round 1
// baseline (1009.165 us; speedup 1.0000x reference)
//
#include <hip/hip_runtime.h>
#include <cstddef>

namespace {
constexpr int kBatch = 32, kH = 512, kW = 512, kCin = 6, kCout = 16, kFs = 5;
constexpr int kOH = kH - kFs + 1, kOW = kW - kFs + 1;  // 508
constexpr int kTile = 32;                 // output tile per block (32x32)
constexpr int kIT = kTile + kFs - 1;      // 36 input rows/cols with halo
constexpr int kRowB = kIT * kCin;         // 216 floats per LDS input row
constexpr int kWElems = kFs * kFs * kCin * kCout;  // 2400
}  // namespace

// Assemble dense [5][5][6][16] kernel (o contiguous) from the sparse tables.
__global__ void assemble_weights(const float* __restrict__ w3,
                                 const float* __restrict__ w4,
                                 const float* __restrict__ w44,
                                 const float* __restrict__ w6,
                                 float* __restrict__ wd) {
  int i = blockIdx.x * blockDim.x + threadIdx.x;
  if (i >= kWElems) return;
  int o = i & 15;                 // output channel
  int c = (i >> 4) % kCin;        // input channel
  int p = i / (kCout * kCin);     // ky*5+kx
  float val = 0.f;
  if (o < 6) {
    int m = (c - o + 6) % 6;
    if (m < 3) val = w3[(p * 3 + m) * 6 + o];
  } else if (o < 12) {
    int k = o - 6;
    int m = (c - k + 6) % 6;
    if (m < 4) val = w4[(p * 4 + m) * 6 + k];
  } else if (o < 15) {
    int k = o - 12;
    int d = (c - k + 6) % 6;
    int m = (d == 0) ? 0 : (d == 1) ? 1 : (d == 3) ? 2 : (d == 4) ? 3 : -1;
    if (m >= 0) val = w44[(p * 4 + m) * 3 + k];
  } else {
    val = w6[p * 6 + c];
  }
  wd[i] = val;
}

// 16 FMAs for pixel slot P using input value from LDS and w0..w3 in regs.
#define FMA16(P)                                                                      \
  {                                                                                   \
    float v = s_in[(ty + ((P) >> 1) * 16 + ky) * kRowB + (tx + ((P)&1) * 16 + kx) * kCin + c]; \
    acc[P][0].x += v * w0.x; acc[P][0].y += v * w0.y; acc[P][0].z += v * w0.z; acc[P][0].w += v * w0.w; \
    acc[P][1].x += v * w1.x; acc[P][1].y += v * w1.y; acc[P][1].z += v * w1.z; acc[P][1].w += v * w1.w; \
    acc[P][2].x += v * w2.x; acc[P][2].y += v * w2.y; acc[P][2].z += v * w2.z; acc[P][2].w += v * w2.w; \
    acc[P][3].x += v * w3.x; acc[P][3].y += v * w3.y; acc[P][3].z += v * w3.z; acc[P][3].w += v * w3.w; \
  }

__global__ __launch_bounds__(256) void conv_sparse(
    const float* __restrict__ in, const float* __restrict__ wd,
    const float* __restrict__ bias, float* __restrict__ out) {
  __shared__ float s_in[kIT * kRowB];  // 36*216 = 7776 floats (31.1 KB)
  __shared__ float s_w[kWElems];       // 2400 floats (9.6 KB)

  const int t = threadIdx.x;
  const int bx0 = blockIdx.x * kTile, by0 = blockIdx.y * kTile;
  const int b = blockIdx.z;

  // Stage dense weights.
  for (int i = t; i < kWElems; i += 256) s_w[i] = wd[i];

  // Stage input tile (rows are contiguous in global: 216 floats each).
  const float* inb = in + (size_t)b * kH * kW * kCin;
  const bool interior = (bx0 + kIT <= kW) && (by0 + kIT <= kH);
  if (interior) {
    for (int i = t; i < kIT * kRowB; i += 256) {
      int r = i / kRowB;
      int rem = i - r * kRowB;
      s_in[i] = inb[((size_t)(by0 + r) * kW + bx0) * kCin + rem];
    }
  } else {
    for (int i = t; i < kIT * kRowB; i += 256) {
      int r = i / kRowB;
      int rem = i - r * kRowB;
      int gy = by0 + r;
      int gx = bx0 + rem / kCin;
      float v = 0.f;
      if (gy < kH && gx < kW) v = inb[((size_t)gy * kW + bx0) * kCin + rem];
      s_in[i] = v;
    }
  }
  __syncthreads();

  const int tx = t & 15, ty = t >> 4;

  // Init accumulators with bias (L2-cached broadcast read).
  const float4* bp = (const float4*)bias;
  float4 b0 = bp[0], b1 = bp[1], b2 = bp[2], b3 = bp[3];
  float4 acc[4][4];
#pragma unroll
  for (int p = 0; p < 4; ++p) {
    acc[p][0] = b0; acc[p][1] = b1; acc[p][2] = b2; acc[p][3] = b3;
  }

#pragma unroll 1
  for (int ky = 0; ky < kFs; ++ky) {
#pragma unroll
    for (int kx = 0; kx < kFs; ++kx) {
#pragma unroll
      for (int c = 0; c < kCin; ++c) {
        const float4* wp = (const float4*)&s_w[((ky * kFs + kx) * kCin + c) * kCout];
        float4 w0 = wp[0], w1 = wp[1], w2 = wp[2], w3 = wp[3];
        FMA16(0)
        FMA16(1)
        FMA16(2)
        FMA16(3)
      }
    }
  }

  // Store 4 pixels x 16 channels (64 B per pixel, aligned).
#pragma unroll
  for (int p = 0; p < 4; ++p) {
    int oy = by0 + ty + (p >> 1) * 16;
    int ox = bx0 + tx + (p & 1) * 16;
    if (oy < kOH && ox < kOW) {
      float4* op = (float4*)&out[(((size_t)b * kOH + oy) * kOW + ox) * kCout];
      op[0] = acc[p][0]; op[1] = acc[p][1]; op[2] = acc[p][2]; op[3] = acc[p][3];
    }
  }
}

extern "C" void kernel_launch(void* const* d_in, const int* in_sizes, int n_in,
                              void* d_out, int out_size, void* d_ws, size_t ws_size,
                              hipStream_t stream) {
  const float* in   = (const float*)d_in[0];
  const float* w3   = (const float*)d_in[1];
  const float* w4   = (const float*)d_in[2];
  const float* w44  = (const float*)d_in[3];
  const float* w6   = (const float*)d_in[4];
  const float* bias = (const float*)d_in[5];
  float* out = (float*)d_out;
  float* wd  = (float*)d_ws;  // 2400 floats of scratch

  assemble_weights<<<(kWElems + 255) / 256, 256, 0, stream>>>(w3, w4, w44, w6, wd);

  dim3 grid((kOW + kTile - 1) / kTile, (kOH + kTile - 1) / kTile, kBatch);
  conv_sparse<<<grid, 256, 0, stream>>>(in, wd, bias, out);
}